// Round 5
// baseline (3314.422 us; speedup 1.0000x reference)
//
#include <hip/hip_runtime.h>
#include <math.h>

#define E 8
#define S 6000
#define D 128
#define A 16
#define L 64
#define H 256
#define C 64
#define B 50
#define T 120
#define NSUB 2
#define FLAT 208      // L + A + D
#define RTOT 400      // E * B
#define RPB 10
#define NBLK (RTOT / RPB)   // 40, 5 blocks per e
#define BGRP 10
#define NBG 5

#define DT 0.5f
#define SQDT 0.70710678118654752440f

#define GNT 4096
#define GYMIN (-128.0f)
#define GDY 0.0625f
#define GINVDY 16.0f

typedef __attribute__((ext_vector_type(8))) short bf16x8;
typedef __attribute__((ext_vector_type(4))) float f32x4;

#define MFMA16(a, b, c) __builtin_amdgcn_mfma_f32_16x16x32_bf16(a, b, c, 0, 0, 0)

__device__ __forceinline__ float sigf(float x) { return 1.0f / (1.0f + __expf(-x)); }

__device__ __forceinline__ unsigned short f2bf(float x) {
    union { float f; unsigned u; } v; v.f = x;
    unsigned r = (v.u + 0x7FFFu + ((v.u >> 16) & 1u)) >> 16;
    return (unsigned short)r;
}

// ---------------------------------------------------------------- g table
__global__ void gtab_kernel(const float* __restrict__ gw1, const float* __restrict__ gb1,
                            const float* __restrict__ gw2, const float* __restrict__ gb2,
                            float* __restrict__ tab) {
    int idx = blockIdx.x * blockDim.x + threadIdx.x;
    if (idx >= L * GNT) return;
    int l = idx / GNT, i = idx % GNT;
    float y = GYMIN + (float)i * GDY;
    const float* w1 = gw1 + l * H;
    const float* b1 = gb1 + l * H;
    const float* w2 = gw2 + l * H;
    float acc = gb2[l];
    #pragma unroll 4
    for (int h = 0; h < H; ++h) acc += w2[h] * sigf(y * w1[h] + b1[h]);
    tab[idx] = acc;
}

// ---------------------------------------------------------------- B-fragment pack (bf16)
__global__ void packB_kernel(const float* __restrict__ src, unsigned short* __restrict__ dst,
                             int K, int N) {
    int idx = blockIdx.x * 256 + threadIdx.x;
    if (idx >= K * N) return;
    int j = idx & 7;
    int lane = (idx >> 3) & 63;
    int t2 = idx >> 9;               // n*(K/32) + kc
    int KC = K >> 5;
    int kc = t2 % KC, n = t2 / KC;
    int k = (kc << 5) + ((lane >> 4) << 3) + j;
    int c = (n << 4) + (lane & 15);
    dst[idx] = f2bf(src[k * N + c]);
}

// act_w z-rows per e -> bf16 fragments
__global__ void packAW_kernel(const float* __restrict__ aw, unsigned short* __restrict__ dst) {
    int idx = blockIdx.x * 256 + threadIdx.x;
    if (idx >= E * L * L) return;
    int e = idx >> 12;
    int rem = idx & 4095;
    int j = rem & 7;
    int lane = (rem >> 3) & 63;
    int t2 = rem >> 9;               // n*2 + kc
    int kc = t2 & 1, n = t2 >> 1;
    int k = (kc << 5) + ((lane >> 4) << 3) + j;
    int c = (n << 4) + (lane & 15);
    dst[idx] = f2bf(aw[((size_t)e * FLAT + k) * L + c]);
}

// ---------------------------------------------------------------- encoder + KL (+ z0 at t=0)
__global__ __launch_bounds__(256) void enc_kernel(const float* __restrict__ xs, const float* __restrict__ z0n,
                           const float* __restrict__ ew1, const float* __restrict__ eb1,
                           const float* __restrict__ ew2, const float* __restrict__ eb2,
                           const float* __restrict__ qw,  const float* __restrict__ qb,
                           const float* __restrict__ pm,  const float* __restrict__ pl,
                           float* __restrict__ z0buf, float* __restrict__ logqp0p) {
    int bid = blockIdx.x;            // (t*E + e)*NBG + bg
    int bg = bid % NBG; int te = bid / NBG; int e = te % E; int t = te / E;
    int tid = threadIdx.x;           // 256
    __shared__ float xsh[BGRP][D];
    __shared__ float c1s[BGRP][H];
    __shared__ float part[4][C][BGRP];
    __shared__ float ctxs[BGRP][C];
    __shared__ float qs[BGRP][2 * L];

    for (int i = tid; i < BGRP * D; i += 256) {
        int j = i / D, d = i % D;
        xsh[j][d] = xs[((size_t)e * S + (size_t)t * B + bg * BGRP + j) * D + d];
    }
    __syncthreads();
    {
        float bias = eb1[e * H + tid];
        float acc[BGRP];
        #pragma unroll
        for (int j = 0; j < BGRP; ++j) acc[j] = bias;
        const float* w = ew1 + (size_t)e * D * H + tid;
        #pragma unroll 4
        for (int d = 0; d < D; ++d) {
            float wv = w[(size_t)d * H];
            #pragma unroll
            for (int j = 0; j < BGRP; ++j) acc[j] += xsh[j][d] * wv;
        }
        #pragma unroll
        for (int j = 0; j < BGRP; ++j) c1s[j][tid] = sigf(acc[j]);
    }
    __syncthreads();
    {
        int c = tid & 63, kq = tid >> 6;
        float acc[BGRP];
        #pragma unroll
        for (int j = 0; j < BGRP; ++j) acc[j] = 0.f;
        const float* w = ew2 + (size_t)e * H * C + c;
        #pragma unroll 4
        for (int h = kq * 64; h < kq * 64 + 64; ++h) {
            float wv = w[(size_t)h * C];
            #pragma unroll
            for (int j = 0; j < BGRP; ++j) acc[j] += c1s[j][h] * wv;
        }
        #pragma unroll
        for (int j = 0; j < BGRP; ++j) part[kq][c][j] = acc[j];
    }
    __syncthreads();
    if (tid < C) {
        float bias = eb2[e * C + tid];
        #pragma unroll
        for (int j = 0; j < BGRP; ++j)
            ctxs[j][tid] = part[0][tid][j] + part[1][tid][j] + part[2][tid][j] + part[3][tid][j] + bias;
    }
    __syncthreads();
    if (tid < 2 * L) {
        float bias = qb[e * 2 * L + tid];
        float acc[BGRP];
        #pragma unroll
        for (int j = 0; j < BGRP; ++j) acc[j] = bias;
        const float* w = qw + (size_t)e * C * 2 * L + tid;
        #pragma unroll 4
        for (int c = 0; c < C; ++c) {
            float wv = w[(size_t)c * 2 * L];
            #pragma unroll
            for (int j = 0; j < BGRP; ++j) acc[j] += ctxs[j][c] * wv;
        }
        #pragma unroll
        for (int j = 0; j < BGRP; ++j) qs[j][tid] = acc[j];
    }
    __syncthreads();
    if (tid < L) {
        int l = tid;
        float kacc = 0.f;
        float m = pm[e * L + l], ls = pl[e * L + l];
        float inv2e = 1.0f / (2.0f * __expf(2.0f * ls));
        #pragma unroll
        for (int j = 0; j < BGRP; ++j) {
            float qm = qs[j][l], ql = qs[j][L + l];
            if (t == 0) {
                int b = bg * BGRP + j;
                float n = z0n[((size_t)e * B + b) * L + l];
                z0buf[((size_t)e * B + b) * L + l] = qm + __expf(ql) * n;
            }
            float dq = qm - m;
            kacc += ls - ql + (__expf(2.f * ql) + dq * dq) * inv2e - 0.5f;
        }
        #pragma unroll
        for (int off = 32; off; off >>= 1) kacc += __shfl_xor(kacc, off);
        if (l == 0) logqp0p[bid] = kacc / (float)B;
    }
}

// ---------------------------------------------------------------- action/x part of z_enc
__global__ __launch_bounds__(64) void ax_kernel(const float* __restrict__ xs, const float* __restrict__ actions,
                          const float* __restrict__ aw, const float* __restrict__ ab,
                          float* __restrict__ ax) {
    int bid = blockIdx.x;            // (t*E + e)*NBG + bg
    int bg = bid % NBG; int te = bid / NBG; int e = te % E; int t = te / E;
    int tid = threadIdx.x;           // 64
    __shared__ float xrow[BGRP][D];
    __shared__ float arow[BGRP][A];
    for (int i = tid; i < BGRP * D; i += 64) {
        int j = i / D, d = i % D;
        xrow[j][d] = xs[((size_t)e * S + (size_t)t * B + bg * BGRP + j) * D + d];
    }
    for (int i = tid; i < BGRP * A; i += 64) {
        int j = i / A, a = i % A;
        arow[j][a] = actions[((size_t)e * S + (size_t)t * B + bg * BGRP + j) * A + a];
    }
    __syncthreads();
    int l = tid;
    float acc[BGRP];
    float bias = ab[e * L + l];
    #pragma unroll
    for (int j = 0; j < BGRP; ++j) acc[j] = bias;
    const float* awp = aw + ((size_t)e * FLAT + L) * L + l;
    #pragma unroll 4
    for (int a = 0; a < A; ++a) {
        float wv = awp[(size_t)a * L];
        #pragma unroll
        for (int j = 0; j < BGRP; ++j) acc[j] += arow[j][a] * wv;
    }
    const float* xwp = aw + ((size_t)e * FLAT + L + A) * L + l;
    #pragma unroll 4
    for (int d = 0; d < D; ++d) {
        float wv = xwp[(size_t)d * L];
        #pragma unroll
        for (int j = 0; j < BGRP; ++j) acc[j] += xrow[j][d] * wv;
    }
    size_t rbase = (size_t)t * RTOT + e * B + bg * BGRP;
    #pragma unroll
    for (int j = 0; j < BGRP; ++j) ax[(rbase + j) * L + l] = acc[j];
}

// ---------------------------------------------------------------- sequential SDE loop
// 16 waves/block (4/SIMD). Per-wave chains halved; stage c K-split; gtab prefetched early.
__global__ __launch_bounds__(1024, 4) void seq_kernel(
    const unsigned short* __restrict__ pkAW, const float* __restrict__ dW,
    const float* __restrict__ z0buf, const float* __restrict__ axbuf,
    const unsigned short* __restrict__ pk1, const unsigned short* __restrict__ pk2,
    const unsigned short* __restrict__ pk3,
    const float* __restrict__ fb1, const float* __restrict__ hb1,
    const float* __restrict__ fb2, const float* __restrict__ hb2,
    const float* __restrict__ fb3, const float* __restrict__ hb3,
    const float* __restrict__ gtab, float* __restrict__ z_all, float* __restrict__ rowlr)
{
    __shared__ __align__(16) bf16x8 w1L[4096];                 // 64 KB stage-a weights (both nets)
    __shared__ __align__(16) unsigned short ybf[16 * 64];      // 2 KB
    __shared__ __align__(16) unsigned short o1[2][16 * 256];   // 16 KB
    __shared__ __align__(16) unsigned short o2[2][16 * 256];   // 16 KB
    __shared__ float fh2[2][2][RPB][64];                       // 10 KB (net, k-half)
    __shared__ float zcS[16][64], zhA[16][64], zhB[16][64];    // 12 KB
    __shared__ float fzb[2][RPB][64], gzb[2][RPB][64];         // 10 KB
    __shared__ float lfb[2][RPB], lcS[RPB], lrsum[RPB];

    int tid = threadIdx.x;
    int wv = tid >> 6;               // 0..15
    int lane = tid & 63;
    int rA = lane & 15, kg = lane >> 4;
    int sw = (rA & 7) << 3;
    int r_base = blockIdx.x * RPB;
    int e = blockIdx.x / 5;          // 5 blocks per e

    for (int i = tid; i < 4096; i += 1024) w1L[i] = ((const bf16x8*)pk1)[i];

    int net = wv >> 3;               // stage a/b net
    int na = (wv & 7) << 1;          // stage a/b n-tile base (2 tiles per wave)
    int cnet = wv >> 3, crem = wv & 7, n0c = crem >> 1, kh = crem & 1;  // stage c
    int n0 = wv & 3;                 // z_enc tile (waves 0-3)

    bf16x8 W0r[2], W2r[16], W3r[4];
    {
        const bf16x8* p0 = (const bf16x8*)pkAW + (e << 9);
        W0r[0] = p0[(n0 * 2 + 0) * 64 + lane];
        W0r[1] = p0[(n0 * 2 + 1) * 64 + lane];
        const bf16x8* p2 = (const bf16x8*)pk2 + net * 8192;
        #pragma unroll
        for (int i2 = 0; i2 < 2; ++i2)
            #pragma unroll
            for (int kc = 0; kc < 8; ++kc)
                W2r[i2 * 8 + kc] = p2[((na + i2) * 8 + kc) * 64 + lane];
        const bf16x8* p3 = (const bf16x8*)pk3 + cnet * 2048;
        #pragma unroll
        for (int kc = 0; kc < 4; ++kc)
            W3r[kc] = p3[(n0c * 8 + kh * 4 + kc) * 64 + lane];
    }
    float biasA[2], biasB[2], biasC;
    {
        const float* b1 = net ? hb1 : fb1;
        const float* b2 = net ? hb2 : fb2;
        const float* b3 = cnet ? hb3 : fb3;
        biasA[0] = b1[((na + 0) << 4) + rA];
        biasA[1] = b1[((na + 1) << 4) + rA];
        biasB[0] = b2[((na + 0) << 4) + rA];
        biasB[1] = b2[((na + 1) << 4) + rA];
        biasC = kh ? 0.f : b3[(n0c << 4) + rA];
    }

    for (int i = tid; i < 16 * 64; i += 1024) {
        int r = i >> 6;
        float v = (i < RPB * L) ? z0buf[(size_t)r_base * L + i] : 0.f;
        ybf[i ^ ((r & 7) << 3)] = f2bf(v);
    }
    if (tid < RPB) lrsum[tid] = 0.f;
    __syncthreads();

    float gt0 = 1.f, gt1 = 1.f, gfr = 0.f;    // gtab prefetch state (per tid<640 thread)

    auto gprep = [&](float v, int l) {
        float x = (v - GYMIN) * GINVDY;
        x = fminf(fmaxf(x, 0.0f), (float)(GNT - 2) + 0.999f);
        int ii = (int)x;
        gfr = x - (float)ii;
        const float* tl = gtab + ((size_t)l << 12);
        gt0 = tl[ii];
        gt1 = tl[ii + 1];
    };

    auto drift = [&](int bo) {
        // ---- stage a: y[16][64] @ w1 (LDS) -> o1
        {
            bf16x8 A0 = *(const bf16x8*)&ybf[((rA << 6) + (kg << 3)) ^ sw];
            bf16x8 A1 = *(const bf16x8*)&ybf[((rA << 6) + 32 + (kg << 3)) ^ sw];
            f32x4 acc[2];
            #pragma unroll
            for (int i2 = 0; i2 < 2; ++i2) {
                acc[i2] = (f32x4){biasA[i2], biasA[i2], biasA[i2], biasA[i2]};
                acc[i2] = MFMA16(A0, w1L[net * 2048 + ((na + i2) * 2 + 0) * 64 + lane], acc[i2]);
                acc[i2] = MFMA16(A1, w1L[net * 2048 + ((na + i2) * 2 + 1) * 64 + lane], acc[i2]);
            }
            unsigned short* o1n = o1[net];
            #pragma unroll
            for (int i2 = 0; i2 < 2; ++i2) {
                int c = ((na + i2) << 4) + rA;
                #pragma unroll
                for (int rr = 0; rr < 4; ++rr) {
                    int r = (kg << 2) + rr;
                    o1n[((r << 8) + c) ^ ((r & 7) << 3)] = f2bf(sigf(acc[i2][rr]));
                }
            }
        }
        __syncthreads();
        // ---- stage b: h1[16][256] @ w2 (registers) -> o2
        {
            const unsigned short* o1n = o1[net];
            f32x4 acc0 = (f32x4){biasB[0], biasB[0], biasB[0], biasB[0]};
            f32x4 acc1 = (f32x4){biasB[1], biasB[1], biasB[1], biasB[1]};
            #pragma unroll
            for (int kc = 0; kc < 8; ++kc) {
                bf16x8 Ak = *(const bf16x8*)&o1n[((rA << 8) + (kc << 5) + (kg << 3)) ^ sw];
                acc0 = MFMA16(Ak, W2r[kc], acc0);
                acc1 = MFMA16(Ak, W2r[8 + kc], acc1);
            }
            unsigned short* o2n = o2[net];
            #pragma unroll
            for (int rr = 0; rr < 4; ++rr) {
                int r = (kg << 2) + rr;
                int c0 = ((na + 0) << 4) + rA;
                int c1 = ((na + 1) << 4) + rA;
                o2n[((r << 8) + c0) ^ ((r & 7) << 3)] = f2bf(sigf(acc0[rr]));
                o2n[((r << 8) + c1) ^ ((r & 7) << 3)] = f2bf(sigf(acc1[rr]));
            }
        }
        __syncthreads();
        // ---- stage c: h2[16][256] @ w3 (registers), K-split across wave pairs -> fh2
        {
            const unsigned short* o2n = o2[cnet];
            f32x4 acc = (f32x4){biasC, biasC, biasC, biasC};
            #pragma unroll
            for (int kc = 0; kc < 4; ++kc) {
                bf16x8 Ak = *(const bf16x8*)&o2n[((rA << 8) + (((kh << 2) + kc) << 5) + (kg << 3)) ^ sw];
                acc = MFMA16(Ak, W3r[kc], acc);
            }
            int c = (n0c << 4) + rA;
            #pragma unroll
            for (int rr = 0; rr < 4; ++rr) {
                int r = (kg << 2) + rr;
                if (r < RPB) fh2[cnet][kh][r][c] = acc[rr];
            }
        }
        __syncthreads();
        // ---- finalize: combine K-halves, gv from prefetched table, u, lf
        if (wv < RPB) {
            int r = wv, l = lane;
            float fv = fh2[0][0][r][l] + fh2[0][1][r][l];
            float hv = fh2[1][0][r][l] + fh2[1][1][r][l];
            float gv = gt0 * (1.0f - gfr) + gt1 * gfr;
            float u = (fv - hv) / gv;
            fzb[bo][r][l] = fv;
            gzb[bo][r][l] = gv;
            float us = u * u;
            #pragma unroll
            for (int off = 32; off; off >>= 1) us += __shfl_xor(us, off);
            if (l == 0) lfb[bo][r] = 0.5f * us;
        }
        __syncthreads();
    };

    for (int t = 0; t < T; ++t) {
        float ax0 = 0.f, dwA0 = 0.f, dwB0 = 0.f;
        if (tid < RPB * L) {
            ax0  = axbuf[((size_t)t * RTOT + r_base) * L + tid];
            dwA0 = dW[((size_t)(t * 2 + 0) * RTOT + r_base) * L + tid] * SQDT;
            dwB0 = dW[((size_t)(t * 2 + 1) * RTOT + r_base) * L + tid] * SQDT;
        }
        // ---- z_enc = z_in @ act_w[:, :L] (MFMA, waves 0-3; ybf holds z_in)
        if (wv < 4) {
            bf16x8 Z0 = *(const bf16x8*)&ybf[((rA << 6) + (kg << 3)) ^ sw];
            bf16x8 Z1 = *(const bf16x8*)&ybf[((rA << 6) + 32 + (kg << 3)) ^ sw];
            f32x4 acc = (f32x4){0.f, 0.f, 0.f, 0.f};
            acc = MFMA16(Z0, W0r[0], acc);
            acc = MFMA16(Z1, W0r[1], acc);
            int c = (n0 << 4) + rA;
            #pragma unroll
            for (int rr = 0; rr < 4; ++rr)
                zcS[(kg << 2) + rr][c] = acc[rr];
        }
        if (tid < RPB) lcS[tid] = 0.f;
        __syncthreads();
        // ---- finish z_enc: add ax, set zh, refresh ybf, prefetch gtab
        if (tid < RPB * L) {
            int r = tid >> 6, l = tid & 63;
            float v = zcS[r][l] + ax0;
            zcS[r][l] = v; zhA[r][l] = v;
            ybf[tid ^ ((r & 7) << 3)] = f2bf(v);
            gprep(v, l);
        }
        __syncthreads();

        drift(0);

        float (*zh)[64] = zhA;
        float (*zt)[64] = zhB;
        int cur = 0;
        #pragma unroll
        for (int k2 = 0; k2 < NSUB; ++k2) {
            int nxt = cur ^ 1;
            float dwv = k2 ? dwB0 : dwA0;
            if (tid < RPB * L) {
                int r = tid >> 6, l = tid & 63;
                float v = 2.f * zcS[r][l] - zh[r][l] + fzb[cur][r][l] * DT + gzb[cur][r][l] * dwv;
                zt[r][l] = v;
                ybf[tid ^ ((r & 7) << 3)] = f2bf(v);
                gprep(v, l);
            }
            __syncthreads();
            drift(nxt);
            if (tid < RPB * L) {
                int r = tid >> 6, l = tid & 63;
                zcS[r][l] += 0.5f * (fzb[cur][r][l] + fzb[nxt][r][l]) * DT
                           + 0.5f * (gzb[cur][r][l] + gzb[nxt][r][l]) * dwv;
            }
            if (tid < RPB) lcS[tid] += 0.5f * (lfb[cur][tid] + lfb[nxt][tid]) * DT;
            { float (*tmp)[64] = zh; zh = zt; zt = tmp; }
            cur = nxt;
            __syncthreads();
        }
        // ---- step end: store z, refresh ybf for next step's z_enc
        if (tid < RPB * L) {
            int r = tid >> 6;
            float v = zcS[r][tid & 63];
            z_all[((size_t)t * RTOT + r_base) * L + tid] = v;
            ybf[tid ^ ((r & 7) << 3)] = f2bf(v);
        }
        if (tid < RPB) lrsum[tid] += lcS[tid];
        __syncthreads();
    }
    if (tid < RPB) rowlr[r_base + tid] = lrsum[tid];
}

// ---------------------------------------------------------------- projection
__global__ __launch_bounds__(256) void proj_kernel(const float* __restrict__ z_all,
                            const float* __restrict__ pw1, const float* __restrict__ pb1,
                            const float* __restrict__ pw2, const float* __restrict__ pb2,
                            const float* __restrict__ pw3, const float* __restrict__ pb3,
                            float* __restrict__ out) {
    int bid = blockIdx.x;            // (t*E + e)*NBG + bg
    int bg = bid % NBG; int te = bid / NBG; int e = te % E; int t = te / E;
    int tid = threadIdx.x;           // 256
    __shared__ float zs[BGRP][L];
    __shared__ float p1s[BGRP][H];
    __shared__ float p2s[BGRP][H];
    __shared__ float part3[D][BGRP];
    size_t rbase = (size_t)t * RTOT + e * B + bg * BGRP;
    for (int i = tid; i < BGRP * L; i += 256) {
        int j = i >> 6, ll = i & 63;
        zs[j][ll] = z_all[(rbase + j) * L + ll];
    }
    __syncthreads();
    {
        float bias = pb1[e * H + tid];
        float acc[BGRP];
        #pragma unroll
        for (int j = 0; j < BGRP; ++j) acc[j] = bias;
        const float* w = pw1 + (size_t)e * L * H + tid;
        #pragma unroll 4
        for (int k = 0; k < L; ++k) {
            float wv = w[(size_t)k * H];
            #pragma unroll
            for (int j = 0; j < BGRP; ++j) acc[j] += zs[j][k] * wv;
        }
        #pragma unroll
        for (int j = 0; j < BGRP; ++j) p1s[j][tid] = sigf(acc[j]);
    }
    __syncthreads();
    {
        float bias = pb2[e * H + tid];
        float acc[BGRP];
        #pragma unroll
        for (int j = 0; j < BGRP; ++j) acc[j] = bias;
        const float* w = pw2 + (size_t)e * H * H + tid;
        #pragma unroll 4
        for (int k = 0; k < H; ++k) {
            float wv = w[(size_t)k * H];
            #pragma unroll
            for (int j = 0; j < BGRP; ++j) acc[j] += p1s[j][k] * wv;
        }
        #pragma unroll
        for (int j = 0; j < BGRP; ++j) p2s[j][tid] = sigf(acc[j]);
    }
    __syncthreads();
    float acc3[BGRP];
    {
        int dd = tid & 127, kh = tid >> 7;
        #pragma unroll
        for (int j = 0; j < BGRP; ++j) acc3[j] = 0.f;
        const float* w = pw3 + (size_t)e * H * D + dd;
        #pragma unroll 4
        for (int k = kh * 128; k < kh * 128 + 128; ++k) {
            float wv = w[(size_t)k * D];
            #pragma unroll
            for (int j = 0; j < BGRP; ++j) acc3[j] += p2s[j][k] * wv;
        }
        if (kh == 1) {
            #pragma unroll
            for (int j = 0; j < BGRP; ++j) part3[dd][j] = acc3[j];
        }
    }
    __syncthreads();
    if (tid < D) {
        float bias = pb3[e * D + tid];
        #pragma unroll
        for (int j = 0; j < BGRP; ++j) {
            out[8 + ((size_t)e * S + (size_t)t * B + bg * BGRP + j) * D + tid]
                = acc3[j] + part3[tid][j] + bias;
        }
    }
}

// ---------------------------------------------------------------- final combine
__global__ void fin_kernel(const float* __restrict__ logqp0p, const float* __restrict__ rowlr,
                           float* __restrict__ out) {
    int e = threadIdx.x;
    if (e < E) {
        float acc = 0.f;
        for (int t = 0; t < T; ++t)
            for (int bg = 0; bg < NBG; ++bg)
                acc += logqp0p[(t * E + e) * NBG + bg];
        float s = 0.f;
        for (int b = 0; b < B; ++b) s += rowlr[e * B + b];
        out[e] = acc + s / (float)B;
    }
}

extern "C" void kernel_launch(void* const* d_in, const int* in_sizes, int n_in,
                              void* d_out, int out_size, void* d_ws, size_t ws_size,
                              hipStream_t stream) {
    const float* xs      = (const float*)d_in[0];
    const float* actions = (const float*)d_in[1];
    const float* z0n     = (const float*)d_in[2];
    const float* dWp     = (const float*)d_in[3];
    const float* ew1     = (const float*)d_in[4];
    const float* eb1     = (const float*)d_in[5];
    const float* ew2     = (const float*)d_in[6];
    const float* eb2     = (const float*)d_in[7];
    const float* qw      = (const float*)d_in[8];
    const float* qb      = (const float*)d_in[9];
    const float* aw      = (const float*)d_in[10];
    const float* ab      = (const float*)d_in[11];
    const float* fw1     = (const float*)d_in[12];
    const float* fb1     = (const float*)d_in[13];
    const float* fw2     = (const float*)d_in[14];
    const float* fb2     = (const float*)d_in[15];
    const float* fw3     = (const float*)d_in[16];
    const float* fb3     = (const float*)d_in[17];
    const float* hw1     = (const float*)d_in[18];
    const float* hb1     = (const float*)d_in[19];
    const float* hw2     = (const float*)d_in[20];
    const float* hb2     = (const float*)d_in[21];
    const float* hw3     = (const float*)d_in[22];
    const float* hb3     = (const float*)d_in[23];
    const float* gw1     = (const float*)d_in[24];
    const float* gb1     = (const float*)d_in[25];
    const float* gw2     = (const float*)d_in[26];
    const float* gb2     = (const float*)d_in[27];
    const float* pw1     = (const float*)d_in[28];
    const float* pb1     = (const float*)d_in[29];
    const float* pw2     = (const float*)d_in[30];
    const float* pb2     = (const float*)d_in[31];
    const float* pw3     = (const float*)d_in[32];
    const float* pb3     = (const float*)d_in[33];
    const float* pm      = (const float*)d_in[34];
    const float* pl      = (const float*)d_in[35];

    float* ws      = (float*)d_ws;
    float* z0buf   = ws;                       // 25600
    float* axbuf   = z0buf + 25600;            // 3072000
    float* z_all   = axbuf + 3072000;          // 3072000
    float* logqp0p = z_all + 3072000;          // 4800
    float* rowlr   = logqp0p + 4800;           // 400
    float* gtab    = rowlr + 400;              // 262144
    unsigned short* pku = (unsigned short*)(gtab + 262144);
    unsigned short* pk1 = pku;                 // 2*16384
    unsigned short* pk2 = pk1 + 32768;         // 2*65536
    unsigned short* pk3 = pk2 + 131072;        // 2*16384
    unsigned short* pkAW = pk3 + 32768;        // E*4096
    float* out     = (float*)d_out;

    packB_kernel<<<64,  256, 0, stream>>>(fw1, pk1,          64, 256);
    packB_kernel<<<64,  256, 0, stream>>>(hw1, pk1 + 16384,  64, 256);
    packB_kernel<<<256, 256, 0, stream>>>(fw2, pk2,          256, 256);
    packB_kernel<<<256, 256, 0, stream>>>(hw2, pk2 + 65536,  256, 256);
    packB_kernel<<<64,  256, 0, stream>>>(fw3, pk3,          256, 64);
    packB_kernel<<<64,  256, 0, stream>>>(hw3, pk3 + 16384,  256, 64);
    packAW_kernel<<<128, 256, 0, stream>>>(aw, pkAW);
    gtab_kernel<<<1024, 256, 0, stream>>>(gw1, gb1, gw2, gb2, gtab);
    enc_kernel<<<T * E * NBG, 256, 0, stream>>>(xs, z0n, ew1, eb1, ew2, eb2, qw, qb, pm, pl, z0buf, logqp0p);
    ax_kernel<<<T * E * NBG, 64, 0, stream>>>(xs, actions, aw, ab, axbuf);
    seq_kernel<<<NBLK, 1024, 0, stream>>>(pkAW, dWp, z0buf, axbuf,
                                          pk1, pk2, pk3,
                                          fb1, hb1, fb2, hb2, fb3, hb3,
                                          gtab, z_all, rowlr);
    proj_kernel<<<T * E * NBG, 256, 0, stream>>>(z_all, pw1, pb1, pw2, pb2, pw3, pb3, out);
    fin_kernel<<<1, 64, 0, stream>>>(logqp0p, rowlr, out);
}

// Round 6
// 2972.721 us; speedup vs baseline: 1.1149x; 1.1149x over previous
//
#include <hip/hip_runtime.h>
#include <math.h>

#define E 8
#define S 6000
#define D 128
#define A 16
#define L 64
#define H 256
#define C 64
#define B 50
#define T 120
#define NSUB 2
#define FLAT 208      // L + A + D
#define RTOT 400      // E * B
#define RPB 10
#define NBLK (RTOT / RPB)   // 40, 5 blocks per e
#define BGRP 10
#define NBG 5

#define DT 0.5f
#define SQDT 0.70710678118654752440f

#define GNT 4096
#define GYMIN (-128.0f)
#define GDY 0.0625f
#define GINVDY 16.0f

typedef __attribute__((ext_vector_type(8))) short bf16x8;
typedef __attribute__((ext_vector_type(4))) float f32x4;

#define MFMA16(a, b, c) __builtin_amdgcn_mfma_f32_16x16x32_bf16(a, b, c, 0, 0, 0)

__device__ __forceinline__ float sigf(float x) { return 1.0f / (1.0f + __expf(-x)); }

__device__ __forceinline__ unsigned short f2bf(float x) {
    union { float f; unsigned u; } v; v.f = x;
    unsigned r = (v.u + 0x7FFFu + ((v.u >> 16) & 1u)) >> 16;
    return (unsigned short)r;
}

// ---------------------------------------------------------------- g table
__global__ void gtab_kernel(const float* __restrict__ gw1, const float* __restrict__ gb1,
                            const float* __restrict__ gw2, const float* __restrict__ gb2,
                            float* __restrict__ tab) {
    int idx = blockIdx.x * blockDim.x + threadIdx.x;
    if (idx >= L * GNT) return;
    int l = idx / GNT, i = idx % GNT;
    float y = GYMIN + (float)i * GDY;
    const float* w1 = gw1 + l * H;
    const float* b1 = gb1 + l * H;
    const float* w2 = gw2 + l * H;
    float acc = gb2[l];
    #pragma unroll 4
    for (int h = 0; h < H; ++h) acc += w2[h] * sigf(y * w1[h] + b1[h]);
    tab[idx] = acc;
}

// ---------------------------------------------------------------- B-fragment pack (bf16)
__global__ void packB_kernel(const float* __restrict__ src, unsigned short* __restrict__ dst,
                             int K, int N) {
    int idx = blockIdx.x * 256 + threadIdx.x;
    if (idx >= K * N) return;
    int j = idx & 7;
    int lane = (idx >> 3) & 63;
    int t2 = idx >> 9;               // n*(K/32) + kc
    int KC = K >> 5;
    int kc = t2 % KC, n = t2 / KC;
    int k = (kc << 5) + ((lane >> 4) << 3) + j;
    int c = (n << 4) + (lane & 15);
    dst[idx] = f2bf(src[k * N + c]);
}

// act_w z-rows per e -> bf16 fragments
__global__ void packAW_kernel(const float* __restrict__ aw, unsigned short* __restrict__ dst) {
    int idx = blockIdx.x * 256 + threadIdx.x;
    if (idx >= E * L * L) return;
    int e = idx >> 12;
    int rem = idx & 4095;
    int j = rem & 7;
    int lane = (rem >> 3) & 63;
    int t2 = rem >> 9;               // n*2 + kc
    int kc = t2 & 1, n = t2 >> 1;
    int k = (kc << 5) + ((lane >> 4) << 3) + j;
    int c = (n << 4) + (lane & 15);
    dst[idx] = f2bf(aw[((size_t)e * FLAT + k) * L + c]);
}

// ---------------------------------------------------------------- encoder + KL (+ z0 at t=0)
__global__ __launch_bounds__(256) void enc_kernel(const float* __restrict__ xs, const float* __restrict__ z0n,
                           const float* __restrict__ ew1, const float* __restrict__ eb1,
                           const float* __restrict__ ew2, const float* __restrict__ eb2,
                           const float* __restrict__ qw,  const float* __restrict__ qb,
                           const float* __restrict__ pm,  const float* __restrict__ pl,
                           float* __restrict__ z0buf, float* __restrict__ logqp0p) {
    int bid = blockIdx.x;            // (t*E + e)*NBG + bg
    int bg = bid % NBG; int te = bid / NBG; int e = te % E; int t = te / E;
    int tid = threadIdx.x;           // 256
    __shared__ float xsh[BGRP][D];
    __shared__ float c1s[BGRP][H];
    __shared__ float part[4][C][BGRP];
    __shared__ float ctxs[BGRP][C];
    __shared__ float qs[BGRP][2 * L];

    for (int i = tid; i < BGRP * D; i += 256) {
        int j = i / D, d = i % D;
        xsh[j][d] = xs[((size_t)e * S + (size_t)t * B + bg * BGRP + j) * D + d];
    }
    __syncthreads();
    {
        float bias = eb1[e * H + tid];
        float acc[BGRP];
        #pragma unroll
        for (int j = 0; j < BGRP; ++j) acc[j] = bias;
        const float* w = ew1 + (size_t)e * D * H + tid;
        #pragma unroll 4
        for (int d = 0; d < D; ++d) {
            float wv = w[(size_t)d * H];
            #pragma unroll
            for (int j = 0; j < BGRP; ++j) acc[j] += xsh[j][d] * wv;
        }
        #pragma unroll
        for (int j = 0; j < BGRP; ++j) c1s[j][tid] = sigf(acc[j]);
    }
    __syncthreads();
    {
        int c = tid & 63, kq = tid >> 6;
        float acc[BGRP];
        #pragma unroll
        for (int j = 0; j < BGRP; ++j) acc[j] = 0.f;
        const float* w = ew2 + (size_t)e * H * C + c;
        #pragma unroll 4
        for (int h = kq * 64; h < kq * 64 + 64; ++h) {
            float wv = w[(size_t)h * C];
            #pragma unroll
            for (int j = 0; j < BGRP; ++j) acc[j] += c1s[j][h] * wv;
        }
        #pragma unroll
        for (int j = 0; j < BGRP; ++j) part[kq][c][j] = acc[j];
    }
    __syncthreads();
    if (tid < C) {
        float bias = eb2[e * C + tid];
        #pragma unroll
        for (int j = 0; j < BGRP; ++j)
            ctxs[j][tid] = part[0][tid][j] + part[1][tid][j] + part[2][tid][j] + part[3][tid][j] + bias;
    }
    __syncthreads();
    if (tid < 2 * L) {
        float bias = qb[e * 2 * L + tid];
        float acc[BGRP];
        #pragma unroll
        for (int j = 0; j < BGRP; ++j) acc[j] = bias;
        const float* w = qw + (size_t)e * C * 2 * L + tid;
        #pragma unroll 4
        for (int c = 0; c < C; ++c) {
            float wv = w[(size_t)c * 2 * L];
            #pragma unroll
            for (int j = 0; j < BGRP; ++j) acc[j] += ctxs[j][c] * wv;
        }
        #pragma unroll
        for (int j = 0; j < BGRP; ++j) qs[j][tid] = acc[j];
    }
    __syncthreads();
    if (tid < L) {
        int l = tid;
        float kacc = 0.f;
        float m = pm[e * L + l], ls = pl[e * L + l];
        float inv2e = 1.0f / (2.0f * __expf(2.0f * ls));
        #pragma unroll
        for (int j = 0; j < BGRP; ++j) {
            float qm = qs[j][l], ql = qs[j][L + l];
            if (t == 0) {
                int b = bg * BGRP + j;
                float n = z0n[((size_t)e * B + b) * L + l];
                z0buf[((size_t)e * B + b) * L + l] = qm + __expf(ql) * n;
            }
            float dq = qm - m;
            kacc += ls - ql + (__expf(2.f * ql) + dq * dq) * inv2e - 0.5f;
        }
        #pragma unroll
        for (int off = 32; off; off >>= 1) kacc += __shfl_xor(kacc, off);
        if (l == 0) logqp0p[bid] = kacc / (float)B;
    }
}

// ---------------------------------------------------------------- action/x part of z_enc
__global__ __launch_bounds__(64) void ax_kernel(const float* __restrict__ xs, const float* __restrict__ actions,
                          const float* __restrict__ aw, const float* __restrict__ ab,
                          float* __restrict__ ax) {
    int bid = blockIdx.x;            // (t*E + e)*NBG + bg
    int bg = bid % NBG; int te = bid / NBG; int e = te % E; int t = te / E;
    int tid = threadIdx.x;           // 64
    __shared__ float xrow[BGRP][D];
    __shared__ float arow[BGRP][A];
    for (int i = tid; i < BGRP * D; i += 64) {
        int j = i / D, d = i % D;
        xrow[j][d] = xs[((size_t)e * S + (size_t)t * B + bg * BGRP + j) * D + d];
    }
    for (int i = tid; i < BGRP * A; i += 64) {
        int j = i / A, a = i % A;
        arow[j][a] = actions[((size_t)e * S + (size_t)t * B + bg * BGRP + j) * A + a];
    }
    __syncthreads();
    int l = tid;
    float acc[BGRP];
    float bias = ab[e * L + l];
    #pragma unroll
    for (int j = 0; j < BGRP; ++j) acc[j] = bias;
    const float* awp = aw + ((size_t)e * FLAT + L) * L + l;
    #pragma unroll 4
    for (int a = 0; a < A; ++a) {
        float wv = awp[(size_t)a * L];
        #pragma unroll
        for (int j = 0; j < BGRP; ++j) acc[j] += arow[j][a] * wv;
    }
    const float* xwp = aw + ((size_t)e * FLAT + L + A) * L + l;
    #pragma unroll 4
    for (int d = 0; d < D; ++d) {
        float wv = xwp[(size_t)d * L];
        #pragma unroll
        for (int j = 0; j < BGRP; ++j) acc[j] += xrow[j][d] * wv;
    }
    size_t rbase = (size_t)t * RTOT + e * B + bg * BGRP;
    #pragma unroll
    for (int j = 0; j < BGRP; ++j) ax[(rbase + j) * L + l] = acc[j];
}

// ---------------------------------------------------------------- sequential SDE loop
// Single-owner register dataflow: thread tid=r*64+l owns all per-element SDE state.
// 14 sync-phases/step (vs 19). W2/W3 register-resident; W1,W0 LDS.
__global__ __launch_bounds__(1024, 4) void seq_kernel(
    const unsigned short* __restrict__ pkAW, const float* __restrict__ dW,
    const float* __restrict__ z0buf, const float* __restrict__ axbuf,
    const unsigned short* __restrict__ pk1, const unsigned short* __restrict__ pk2,
    const unsigned short* __restrict__ pk3,
    const float* __restrict__ fb1, const float* __restrict__ hb1,
    const float* __restrict__ fb2, const float* __restrict__ hb2,
    const float* __restrict__ fb3, const float* __restrict__ hb3,
    const float* __restrict__ gtab, float* __restrict__ z_all, float* __restrict__ rowlr)
{
    __shared__ __align__(16) bf16x8 w1L[64 * 64];              // 64 KB [slot][lane]
    __shared__ __align__(16) bf16x8 w0L[8 * 64];               // 8 KB  [slot][lane]
    __shared__ __align__(16) unsigned short ybf[16 * 64];      // 2 KB  (bf16 y, swizzled)
    __shared__ __align__(16) unsigned short o1[2][16 * 256];   // 16 KB
    __shared__ __align__(16) unsigned short o2[2][16 * 256];   // 16 KB
    __shared__ float fh2[2][2][16][64];                        // 16 KB (net, k-half)
    __shared__ float zcS[16][64];                              // 4 KB (z_enc MFMA out)

    int tid = threadIdx.x;
    int wv = tid >> 6;               // 0..15
    int lane = tid & 63;
    int rA = lane & 15, kg = lane >> 4;
    int sw = (rA & 7) << 3;
    int r_base = blockIdx.x * RPB;
    int e = blockIdx.x / 5;          // 5 blocks per e

    int net = wv >> 3;               // stage a/b net
    int na = (wv & 7) << 1;          // stage a/b n-tile base (2 tiles)
    int cnet = wv >> 3, crem = wv & 7, n0c = crem >> 1, khc = crem & 1;  // stage c

    // ---- LDS weights: W1 (both nets) per-wave slots; W0 (z_enc, this e)
    {
        const bf16x8* p1 = (const bf16x8*)pk1;
        #pragma unroll
        for (int f = 0; f < 4; ++f)
            w1L[(((wv << 2) + f) << 6) + lane] =
                p1[net * 2048 + ((na + (f >> 1)) * 2 + (f & 1)) * 64 + lane];
        if (wv < 4) {
            const bf16x8* p0 = (const bf16x8*)pkAW + (e << 9);
            w0L[(((wv << 1) + 0) << 6) + lane] = p0[(wv * 2 + 0) * 64 + lane];
            w0L[(((wv << 1) + 1) << 6) + lane] = p0[(wv * 2 + 1) * 64 + lane];
        }
    }
    // ---- register-resident W2 (16 frags) and W3 (4 frags)
    bf16x8 W2r[16], W3r[4];
    {
        const bf16x8* p2 = (const bf16x8*)pk2 + net * 8192;
        #pragma unroll
        for (int i2 = 0; i2 < 2; ++i2)
            #pragma unroll
            for (int kc = 0; kc < 8; ++kc)
                W2r[i2 * 8 + kc] = p2[((na + i2) * 8 + kc) * 64 + lane];
        const bf16x8* p3 = (const bf16x8*)pk3 + cnet * 2048;
        #pragma unroll
        for (int kc = 0; kc < 4; ++kc)
            W3r[kc] = p3[(n0c * 8 + khc * 4 + kc) * 64 + lane];
    }
    float biasA0, biasA1, biasB0, biasB1, biasC;
    {
        const float* b1 = net ? hb1 : fb1;
        const float* b2 = net ? hb2 : fb2;
        const float* b3 = cnet ? hb3 : fb3;
        biasA0 = b1[((na + 0) << 4) + rA];
        biasA1 = b1[((na + 1) << 4) + rA];
        biasB0 = b2[((na + 0) << 4) + rA];
        biasB1 = b2[((na + 1) << 4) + rA];
        biasC = khc ? 0.f : b3[(n0c << 4) + rA];
    }

    // ---- owner state (tid < 640: r = tid>>6, l = tid&63)
    int orow = tid >> 6, ol = tid & 63;
    bool owner = (tid < RPB * L);
    float zc_r = 0.f, zh_r = 0.f, fz_r = 0.f, gz_r = 1.f, lf_r = 0.f;
    float lcacc = 0.f, lrs = 0.f;
    float gt0 = 1.f, gt1 = 1.f, gfr = 0.f;
    float ax_r = 0.f, dwA_r = 0.f, dwB_r = 0.f;

    // ---- init ybf from z0 (rows >= RPB zeroed)
    for (int i = tid; i < 16 * 64; i += 1024) {
        int r = i >> 6;
        float v = (i < RPB * L) ? z0buf[(size_t)r_base * L + i] : 0.f;
        ybf[i ^ ((r & 7) << 3)] = f2bf(v);
    }
    __syncthreads();

    auto gprep = [&](float v) {
        float x = (v - GYMIN) * GINVDY;
        x = fminf(fmaxf(x, 0.0f), (float)(GNT - 2) + 0.999f);
        int ii = (int)x;
        gfr = x - (float)ii;
        const float* tl = gtab + ((size_t)ol << 12);
        gt0 = tl[ii];
        gt1 = tl[ii + 1];
    };

    // phases Pa/Pb/Pc of one drift (all waves)
    auto drift3 = [&]() {
        // ---- Pa: y[16][64] @ W1 (LDS) -> o1
        {
            bf16x8 A0 = *(const bf16x8*)&ybf[((rA << 6) + (kg << 3)) ^ sw];
            bf16x8 A1 = *(const bf16x8*)&ybf[((rA << 6) + 32 + (kg << 3)) ^ sw];
            f32x4 acc0 = (f32x4){biasA0, biasA0, biasA0, biasA0};
            f32x4 acc1 = (f32x4){biasA1, biasA1, biasA1, biasA1};
            acc0 = MFMA16(A0, w1L[(((wv << 2) + 0) << 6) + lane], acc0);
            acc0 = MFMA16(A1, w1L[(((wv << 2) + 1) << 6) + lane], acc0);
            acc1 = MFMA16(A0, w1L[(((wv << 2) + 2) << 6) + lane], acc1);
            acc1 = MFMA16(A1, w1L[(((wv << 2) + 3) << 6) + lane], acc1);
            unsigned short* o1n = o1[net];
            int c0 = ((na + 0) << 4) + rA;
            int c1 = ((na + 1) << 4) + rA;
            #pragma unroll
            for (int rr = 0; rr < 4; ++rr) {
                int r = (kg << 2) + rr;
                int rx = (r & 7) << 3;
                o1n[((r << 8) + c0) ^ rx] = f2bf(sigf(acc0[rr]));
                o1n[((r << 8) + c1) ^ rx] = f2bf(sigf(acc1[rr]));
            }
        }
        __syncthreads();
        // ---- Pb: h1[16][256] @ W2 (regs) -> o2
        {
            const unsigned short* o1n = o1[net];
            f32x4 acc0 = (f32x4){biasB0, biasB0, biasB0, biasB0};
            f32x4 acc1 = (f32x4){biasB1, biasB1, biasB1, biasB1};
            #pragma unroll
            for (int kc = 0; kc < 8; ++kc) {
                bf16x8 Ak = *(const bf16x8*)&o1n[((rA << 8) + (kc << 5) + (kg << 3)) ^ sw];
                acc0 = MFMA16(Ak, W2r[kc], acc0);
                acc1 = MFMA16(Ak, W2r[8 + kc], acc1);
            }
            unsigned short* o2n = o2[net];
            int c0 = ((na + 0) << 4) + rA;
            int c1 = ((na + 1) << 4) + rA;
            #pragma unroll
            for (int rr = 0; rr < 4; ++rr) {
                int r = (kg << 2) + rr;
                int rx = (r & 7) << 3;
                o2n[((r << 8) + c0) ^ rx] = f2bf(sigf(acc0[rr]));
                o2n[((r << 8) + c1) ^ rx] = f2bf(sigf(acc1[rr]));
            }
        }
        __syncthreads();
        // ---- Pc: h2[16][256] @ W3 (regs), K-halved across wave pairs -> fh2
        {
            const unsigned short* o2n = o2[cnet];
            f32x4 acc = (f32x4){biasC, biasC, biasC, biasC};
            #pragma unroll
            for (int kc = 0; kc < 4; ++kc) {
                bf16x8 Ak = *(const bf16x8*)&o2n[((rA << 8) + (((khc << 2) + kc) << 5) + (kg << 3)) ^ sw];
                acc = MFMA16(Ak, W3r[kc], acc);
            }
            int c = (n0c << 4) + rA;
            #pragma unroll
            for (int rr = 0; rr < 4; ++rr)
                fh2[cnet][khc][(kg << 2) + rr][c] = acc[rr];
        }
        __syncthreads();
    };

    for (int t = 0; t < T; ++t) {
        // ---- P0: owner global loads + z_enc MFMA (waves 0-3)
        if (owner) {
            ax_r  = axbuf[((size_t)t * RTOT + r_base) * L + tid];
            dwA_r = dW[((size_t)(t * 2 + 0) * RTOT + r_base) * L + tid] * SQDT;
            dwB_r = dW[((size_t)(t * 2 + 1) * RTOT + r_base) * L + tid] * SQDT;
        }
        if (wv < 4) {
            bf16x8 Z0 = *(const bf16x8*)&ybf[((rA << 6) + (kg << 3)) ^ sw];
            bf16x8 Z1 = *(const bf16x8*)&ybf[((rA << 6) + 32 + (kg << 3)) ^ sw];
            f32x4 acc = (f32x4){0.f, 0.f, 0.f, 0.f};
            acc = MFMA16(Z0, w0L[((wv << 1) << 6) + lane], acc);
            acc = MFMA16(Z1, w0L[(((wv << 1) + 1) << 6) + lane], acc);
            int c = (wv << 4) + rA;
            #pragma unroll
            for (int rr = 0; rr < 4; ++rr)
                zcS[(kg << 2) + rr][c] = acc[rr];
        }
        __syncthreads();
        // ---- P1: owner: zenc = zcS + ax -> zc; write ybf; prefetch gtab
        if (owner) {
            float v = zcS[orow][ol] + ax_r;
            zc_r = v;
            ybf[tid ^ ((orow & 7) << 3)] = f2bf(v);
            gprep(v);
        }
        __syncthreads();

        #pragma unroll
        for (int d = 0; d < 3; ++d) {
            drift3();
            // ---- Pf: finalize + Heun update, all in owner registers
            if (owner) {
                float fv = fh2[0][0][orow][ol] + fh2[0][1][orow][ol];
                float hv = fh2[1][0][orow][ol] + fh2[1][1][orow][ol];
                float gv = gt0 * (1.0f - gfr) + gt1 * gfr;
                float uu = (fv - hv) / gv;
                float us = uu * uu;
                #pragma unroll
                for (int off = 32; off; off >>= 1) us += __shfl_xor(us, off);
                float lfd = 0.5f * us;
                if (d == 0) {
                    fz_r = fv; gz_r = gv; lf_r = lfd;
                    float y1 = zc_r + fv * DT + gv * dwA_r;   // zh_n (zc==zh==zini)
                    zh_r = y1;
                    ybf[tid ^ ((orow & 7) << 3)] = f2bf(y1);
                    gprep(y1);
                } else if (d == 1) {
                    zc_r += 0.5f * (fz_r + fv) * DT + 0.5f * (gz_r + gv) * dwA_r;
                    lcacc = 0.5f * (lf_r + lfd) * DT;
                    float y2 = 2.f * zc_r - zh_r + fv * DT + gv * dwB_r;
                    fz_r = fv; gz_r = gv; lf_r = lfd;
                    ybf[tid ^ ((orow & 7) << 3)] = f2bf(y2);
                    gprep(y2);
                } else {
                    zc_r += 0.5f * (fz_r + fv) * DT + 0.5f * (gz_r + gv) * dwB_r;
                    lcacc += 0.5f * (lf_r + lfd) * DT;
                    lrs += lcacc;
                    z_all[((size_t)t * RTOT + r_base) * L + tid] = zc_r;
                    ybf[tid ^ ((orow & 7) << 3)] = f2bf(zc_r);
                }
            }
            __syncthreads();
        }
    }
    if (owner && ol == 0) rowlr[r_base + orow] = lrs;
}

// ---------------------------------------------------------------- projection
__global__ __launch_bounds__(256) void proj_kernel(const float* __restrict__ z_all,
                            const float* __restrict__ pw1, const float* __restrict__ pb1,
                            const float* __restrict__ pw2, const float* __restrict__ pb2,
                            const float* __restrict__ pw3, const float* __restrict__ pb3,
                            float* __restrict__ out) {
    int bid = blockIdx.x;            // (t*E + e)*NBG + bg
    int bg = bid % NBG; int te = bid / NBG; int e = te % E; int t = te / E;
    int tid = threadIdx.x;           // 256
    __shared__ float zs[BGRP][L];
    __shared__ float p1s[BGRP][H];
    __shared__ float p2s[BGRP][H];
    __shared__ float part3[D][BGRP];
    size_t rbase = (size_t)t * RTOT + e * B + bg * BGRP;
    for (int i = tid; i < BGRP * L; i += 256) {
        int j = i >> 6, ll = i & 63;
        zs[j][ll] = z_all[(rbase + j) * L + ll];
    }
    __syncthreads();
    {
        float bias = pb1[e * H + tid];
        float acc[BGRP];
        #pragma unroll
        for (int j = 0; j < BGRP; ++j) acc[j] = bias;
        const float* w = pw1 + (size_t)e * L * H + tid;
        #pragma unroll 4
        for (int k = 0; k < L; ++k) {
            float wv = w[(size_t)k * H];
            #pragma unroll
            for (int j = 0; j < BGRP; ++j) acc[j] += zs[j][k] * wv;
        }
        #pragma unroll
        for (int j = 0; j < BGRP; ++j) p1s[j][tid] = sigf(acc[j]);
    }
    __syncthreads();
    {
        float bias = pb2[e * H + tid];
        float acc[BGRP];
        #pragma unroll
        for (int j = 0; j < BGRP; ++j) acc[j] = bias;
        const float* w = pw2 + (size_t)e * H * H + tid;
        #pragma unroll 4
        for (int k = 0; k < H; ++k) {
            float wv = w[(size_t)k * H];
            #pragma unroll
            for (int j = 0; j < BGRP; ++j) acc[j] += p1s[j][k] * wv;
        }
        #pragma unroll
        for (int j = 0; j < BGRP; ++j) p2s[j][tid] = sigf(acc[j]);
    }
    __syncthreads();
    float acc3[BGRP];
    {
        int dd = tid & 127, kh = tid >> 7;
        #pragma unroll
        for (int j = 0; j < BGRP; ++j) acc3[j] = 0.f;
        const float* w = pw3 + (size_t)e * H * D + dd;
        #pragma unroll 4
        for (int k = kh * 128; k < kh * 128 + 128; ++k) {
            float wv = w[(size_t)k * D];
            #pragma unroll
            for (int j = 0; j < BGRP; ++j) acc3[j] += p2s[j][k] * wv;
        }
        if (kh == 1) {
            #pragma unroll
            for (int j = 0; j < BGRP; ++j) part3[dd][j] = acc3[j];
        }
    }
    __syncthreads();
    if (tid < D) {
        float bias = pb3[e * D + tid];
        #pragma unroll
        for (int j = 0; j < BGRP; ++j) {
            out[8 + ((size_t)e * S + (size_t)t * B + bg * BGRP + j) * D + tid]
                = acc3[j] + part3[tid][j] + bias;
        }
    }
}

// ---------------------------------------------------------------- final combine
__global__ void fin_kernel(const float* __restrict__ logqp0p, const float* __restrict__ rowlr,
                           float* __restrict__ out) {
    int e = threadIdx.x;
    if (e < E) {
        float acc = 0.f;
        for (int t = 0; t < T; ++t)
            for (int bg = 0; bg < NBG; ++bg)
                acc += logqp0p[(t * E + e) * NBG + bg];
        float s = 0.f;
        for (int b = 0; b < B; ++b) s += rowlr[e * B + b];
        out[e] = acc + s / (float)B;
    }
}

extern "C" void kernel_launch(void* const* d_in, const int* in_sizes, int n_in,
                              void* d_out, int out_size, void* d_ws, size_t ws_size,
                              hipStream_t stream) {
    const float* xs      = (const float*)d_in[0];
    const float* actions = (const float*)d_in[1];
    const float* z0n     = (const float*)d_in[2];
    const float* dWp     = (const float*)d_in[3];
    const float* ew1     = (const float*)d_in[4];
    const float* eb1     = (const float*)d_in[5];
    const float* ew2     = (const float*)d_in[6];
    const float* eb2     = (const float*)d_in[7];
    const float* qw      = (const float*)d_in[8];
    const float* qb      = (const float*)d_in[9];
    const float* aw      = (const float*)d_in[10];
    const float* ab      = (const float*)d_in[11];
    const float* fw1     = (const float*)d_in[12];
    const float* fb1     = (const float*)d_in[13];
    const float* fw2     = (const float*)d_in[14];
    const float* fb2     = (const float*)d_in[15];
    const float* fw3     = (const float*)d_in[16];
    const float* fb3     = (const float*)d_in[17];
    const float* hw1     = (const float*)d_in[18];
    const float* hb1     = (const float*)d_in[19];
    const float* hw2     = (const float*)d_in[20];
    const float* hb2     = (const float*)d_in[21];
    const float* hw3     = (const float*)d_in[22];
    const float* hb3     = (const float*)d_in[23];
    const float* gw1     = (const float*)d_in[24];
    const float* gb1     = (const float*)d_in[25];
    const float* gw2     = (const float*)d_in[26];
    const float* gb2     = (const float*)d_in[27];
    const float* pw1     = (const float*)d_in[28];
    const float* pb1     = (const float*)d_in[29];
    const float* pw2     = (const float*)d_in[30];
    const float* pb2     = (const float*)d_in[31];
    const float* pw3     = (const float*)d_in[32];
    const float* pb3     = (const float*)d_in[33];
    const float* pm      = (const float*)d_in[34];
    const float* pl      = (const float*)d_in[35];

    float* ws      = (float*)d_ws;
    float* z0buf   = ws;                       // 25600
    float* axbuf   = z0buf + 25600;            // 3072000
    float* z_all   = axbuf + 3072000;          // 3072000
    float* logqp0p = z_all + 3072000;          // 4800
    float* rowlr   = logqp0p + 4800;           // 400
    float* gtab    = rowlr + 400;              // 262144
    unsigned short* pku = (unsigned short*)(gtab + 262144);
    unsigned short* pk1 = pku;                 // 2*16384
    unsigned short* pk2 = pk1 + 32768;         // 2*65536
    unsigned short* pk3 = pk2 + 131072;        // 2*16384
    unsigned short* pkAW = pk3 + 32768;        // E*4096
    float* out     = (float*)d_out;

    packB_kernel<<<64,  256, 0, stream>>>(fw1, pk1,          64, 256);
    packB_kernel<<<64,  256, 0, stream>>>(hw1, pk1 + 16384,  64, 256);
    packB_kernel<<<256, 256, 0, stream>>>(fw2, pk2,          256, 256);
    packB_kernel<<<256, 256, 0, stream>>>(hw2, pk2 + 65536,  256, 256);
    packB_kernel<<<64,  256, 0, stream>>>(fw3, pk3,          256, 64);
    packB_kernel<<<64,  256, 0, stream>>>(hw3, pk3 + 16384,  256, 64);
    packAW_kernel<<<128, 256, 0, stream>>>(aw, pkAW);
    gtab_kernel<<<1024, 256, 0, stream>>>(gw1, gb1, gw2, gb2, gtab);
    enc_kernel<<<T * E * NBG, 256, 0, stream>>>(xs, z0n, ew1, eb1, ew2, eb2, qw, qb, pm, pl, z0buf, logqp0p);
    ax_kernel<<<T * E * NBG, 64, 0, stream>>>(xs, actions, aw, ab, axbuf);
    seq_kernel<<<NBLK, 1024, 0, stream>>>(pkAW, dWp, z0buf, axbuf,
                                          pk1, pk2, pk3,
                                          fb1, hb1, fb2, hb2, fb3, hb3,
                                          gtab, z_all, rowlr);
    proj_kernel<<<T * E * NBG, 256, 0, stream>>>(z_all, pw1, pb1, pw2, pb2, pw3, pb3, out);
    fin_kernel<<<1, 64, 0, stream>>>(logqp0p, rowlr, out);
}